// Round 1
// baseline (1025.988 us; speedup 1.0000x reference)
//
#include <hip/hip_runtime.h>
#include <math.h>

#define NN 50000
#define NE 500000
#define HID 128
#define EDIM 32

__device__ __forceinline__ float wsum(float v) {
#pragma unroll
  for (int m = 1; m < 64; m <<= 1) v += __shfl_xor(v, m, 64);
  return v;
}

// ---------------- Kernel 1: edge encoder + scatter-add ----------------
// wave handles 8 edges at a time; weights read from global (L1/L2 cached,
// coalesced across lanes), activations broadcast from per-wave LDS.
__global__ __launch_bounds__(256) void enc_kernel(
    const float* __restrict__ ea, const int* __restrict__ ei,
    const float* __restrict__ W1, const float* __restrict__ b1,
    const float* __restrict__ g1, const float* __restrict__ be1,
    const float* __restrict__ W2, const float* __restrict__ b2,
    const float* __restrict__ g2, const float* __restrict__ be2,
    float* __restrict__ aggr, float* __restrict__ cnt) {
  __shared__ float ea_lds[4][8][EDIM];
  __shared__ float h1_lds[4][8][HID];
  const int lane = threadIdx.x & 63;
  const int w = threadIdx.x >> 6;
  const int j0 = lane, j1 = lane + 64;
  const float b1_0 = b1[j0], b1_1 = b1[j1];
  const float g1_0 = g1[j0], g1_1 = g1[j1];
  const float be1_0 = be1[j0], be1_1 = be1[j1];
  const float b2_0 = b2[j0], b2_1 = b2[j1];
  const float g2_0 = g2[j0], g2_1 = g2[j1];
  const float be2_0 = be2[j0], be2_1 = be2[j1];

  const int gwave = blockIdx.x * 4 + w;
  const int nwave = gridDim.x * 4;
  for (int base = gwave * 8; base < NE; base += nwave * 8) {
    // stage 8 edges' attrs (NE % 8 == 0, no tail)
#pragma unroll
    for (int t = 0; t < 4; ++t) {
      int idx = t * 64 + lane;
      int m = idx >> 5, k = idx & 31;
      ea_lds[w][m][k] = ea[(base + m) * EDIM + k];
    }
    __asm__ volatile("s_waitcnt lgkmcnt(0)" ::: "memory");

    float a0[8], a1[8];
#pragma unroll
    for (int m = 0; m < 8; ++m) { a0[m] = b1_0; a1[m] = b1_1; }
#pragma unroll 4
    for (int k = 0; k < EDIM; ++k) {
      float w0 = W1[k * HID + j0];
      float w1 = W1[k * HID + j1];
#pragma unroll
      for (int m = 0; m < 8; ++m) {
        float e = ea_lds[w][m][k];
        a0[m] = fmaf(e, w0, a0[m]);
        a1[m] = fmaf(e, w1, a1[m]);
      }
    }
    // LN1 + relu -> LDS
#pragma unroll
    for (int m = 0; m < 8; ++m) {
      float s = wsum(a0[m] + a1[m]);
      float mu = s * (1.0f / HID);
      float d0 = a0[m] - mu, d1 = a1[m] - mu;
      float q = wsum(d0 * d0 + d1 * d1);
      float inv = rsqrtf(q * (1.0f / HID) + 1e-5f);
      float h0 = fmaxf(d0 * inv * g1_0 + be1_0, 0.0f);
      float h1 = fmaxf(d1 * inv * g1_1 + be1_1, 0.0f);
      h1_lds[w][m][j0] = h0;
      h1_lds[w][m][j1] = h1;
    }
    __asm__ volatile("s_waitcnt lgkmcnt(0)" ::: "memory");

    // layer 2
#pragma unroll
    for (int m = 0; m < 8; ++m) { a0[m] = b2_0; a1[m] = b2_1; }
#pragma unroll 4
    for (int k = 0; k < HID; ++k) {
      float w0 = W2[k * HID + j0];
      float w1 = W2[k * HID + j1];
#pragma unroll
      for (int m = 0; m < 8; ++m) {
        float h = h1_lds[w][m][k];
        a0[m] = fmaf(h, w0, a0[m]);
        a1[m] = fmaf(h, w1, a1[m]);
      }
    }
    // LN2 + relu + scatter
#pragma unroll
    for (int m = 0; m < 8; ++m) {
      float s = wsum(a0[m] + a1[m]);
      float mu = s * (1.0f / HID);
      float d0 = a0[m] - mu, d1 = a1[m] - mu;
      float q = wsum(d0 * d0 + d1 * d1);
      float inv = rsqrtf(q * (1.0f / HID) + 1e-5f);
      float e0 = fmaxf(d0 * inv * g2_0 + be2_0, 0.0f);
      float e1 = fmaxf(d1 * inv * g2_1 + be2_1, 0.0f);
      int srcn = ei[base + m];
      atomicAdd(&aggr[srcn * HID + j0], e0);
      atomicAdd(&aggr[srcn * HID + j1], e1);
      if (lane == 0) atomicAdd(&cnt[srcn], 1.0f);
    }
  }
}

// ---------------- Kernel 2: GRU + u/v precompute ----------------
// wave handles 8 nodes; h_new never hits global memory — directly folded
// into u = h_new@Wc1[0:128], v = h_new@Wc1[128:256].
__global__ __launch_bounds__(256) void gru_kernel(
    const float* __restrict__ aggr, const float* __restrict__ cnt,
    const float* __restrict__ h_prev,
    const float* __restrict__ Wih, const float* __restrict__ bih,
    const float* __restrict__ Whh, const float* __restrict__ bhh,
    const float* __restrict__ Wc1,
    float* __restrict__ u, float* __restrict__ vv) {
  __shared__ float a_lds[4][8][HID];
  __shared__ float h_lds[4][8][HID];
  __shared__ float hn_lds[4][8][HID];
  const int lane = threadIdx.x & 63;
  const int w = threadIdx.x >> 6;
  const int gwave = blockIdx.x * 4 + w;
  const int nwave = gridDim.x * 4;
  const int ntask = NN / 8;  // 6250 exact
  for (int task = gwave; task < ntask; task += nwave) {
    int n0 = task * 8;
#pragma unroll
    for (int t = 0; t < 16; ++t) {
      int idx = t * 64 + lane;
      int m = idx >> 7, k = idx & 127;
      int node = n0 + m;
      float ic = 1.0f / fmaxf(cnt[node], 1.0f);
      a_lds[w][m][k] = aggr[node * HID + k] * ic;
      h_lds[w][m][k] = h_prev[node * HID + k];
    }
    __asm__ volatile("s_waitcnt lgkmcnt(0)" ::: "memory");

#pragma unroll
    for (int j2 = 0; j2 < 2; ++j2) {
      int j = lane + 64 * j2;
      float r[8], z[8];
      {  // gate r
        float ax[8], ah[8];
        float bx = bih[j], bh = bhh[j];
#pragma unroll
        for (int m = 0; m < 8; ++m) { ax[m] = bx; ah[m] = bh; }
        const float* wi = &Wih[j * HID];
        const float* wh = &Whh[j * HID];
#pragma unroll 4
        for (int k = 0; k < HID; ++k) {
          float w1v = wi[k], w2v = wh[k];
#pragma unroll
          for (int m = 0; m < 8; ++m) {
            ax[m] = fmaf(a_lds[w][m][k], w1v, ax[m]);
            ah[m] = fmaf(h_lds[w][m][k], w2v, ah[m]);
          }
        }
#pragma unroll
        for (int m = 0; m < 8; ++m) r[m] = 1.0f / (1.0f + expf(-(ax[m] + ah[m])));
      }
      {  // gate z
        float ax[8], ah[8];
        float bx = bih[128 + j], bh = bhh[128 + j];
#pragma unroll
        for (int m = 0; m < 8; ++m) { ax[m] = bx; ah[m] = bh; }
        const float* wi = &Wih[(128 + j) * HID];
        const float* wh = &Whh[(128 + j) * HID];
#pragma unroll 4
        for (int k = 0; k < HID; ++k) {
          float w1v = wi[k], w2v = wh[k];
#pragma unroll
          for (int m = 0; m < 8; ++m) {
            ax[m] = fmaf(a_lds[w][m][k], w1v, ax[m]);
            ah[m] = fmaf(h_lds[w][m][k], w2v, ah[m]);
          }
        }
#pragma unroll
        for (int m = 0; m < 8; ++m) z[m] = 1.0f / (1.0f + expf(-(ax[m] + ah[m])));
      }
      {  // gate n + combine
        float ax[8], ah[8];
        float bx = bih[256 + j], bh = bhh[256 + j];
#pragma unroll
        for (int m = 0; m < 8; ++m) { ax[m] = bx; ah[m] = bh; }
        const float* wi = &Wih[(256 + j) * HID];
        const float* wh = &Whh[(256 + j) * HID];
#pragma unroll 4
        for (int k = 0; k < HID; ++k) {
          float w1v = wi[k], w2v = wh[k];
#pragma unroll
          for (int m = 0; m < 8; ++m) {
            ax[m] = fmaf(a_lds[w][m][k], w1v, ax[m]);
            ah[m] = fmaf(h_lds[w][m][k], w2v, ah[m]);
          }
        }
#pragma unroll
        for (int m = 0; m < 8; ++m) {
          float nval = tanhf(ax[m] + r[m] * ah[m]);
          float hp = h_lds[w][m][j];
          hn_lds[w][m][j] = (1.0f - z[m]) * nval + z[m] * hp;
        }
      }
    }
    __asm__ volatile("s_waitcnt lgkmcnt(0)" ::: "memory");

    // u = hn@A, v = hn@B  (A=Wc1 rows 0..127, B=rows 128..255)
#pragma unroll
    for (int j2 = 0; j2 < 2; ++j2) {
      int j = lane + 64 * j2;
      float au[8], av[8];
#pragma unroll
      for (int m = 0; m < 8; ++m) { au[m] = 0.f; av[m] = 0.f; }
#pragma unroll 4
      for (int k = 0; k < HID; ++k) {
        float wa = Wc1[k * HID + j];
        float wb = Wc1[(128 + k) * HID + j];
#pragma unroll
        for (int m = 0; m < 8; ++m) {
          float h = hn_lds[w][m][k];
          au[m] = fmaf(h, wa, au[m]);
          av[m] = fmaf(h, wb, av[m]);
        }
      }
#pragma unroll
      for (int m = 0; m < 8; ++m) {
        u[(n0 + m) * HID + j] = au[m];
        vv[(n0 + m) * HID + j] = av[m];
      }
    }
  }
}

// ---------------- Kernel 3: per-edge classifier ----------------
// out[e] = relu(u[src] + v[dst] + ea@C + bc1) @ Wc2 + bc2
__global__ __launch_bounds__(256) void cls_kernel(
    const float* __restrict__ u, const float* __restrict__ vv,
    const float* __restrict__ ea, const int* __restrict__ ei,
    const float* __restrict__ Wc1, const float* __restrict__ bc1,
    const float* __restrict__ Wc2, const float* __restrict__ bc2,
    float* __restrict__ out) {
  __shared__ float C_lds[EDIM * HID];  // 16 KB: Wc1 rows 256..287
  const int lane = threadIdx.x & 63;
  const int w = threadIdx.x >> 6;
  for (int i = threadIdx.x; i < EDIM * HID; i += 256) C_lds[i] = Wc1[256 * HID + i];
  __syncthreads();
  const float bc1_0 = bc1[lane], bc1_1 = bc1[lane + 64];
  const float w2_0 = Wc2[lane], w2_1 = Wc2[lane + 64];
  const float bcc = bc2[0];

  const int gwave = blockIdx.x * 4 + w;
  const int nwave = gridDim.x * 4;
  for (int e = gwave; e < NE; e += nwave) {
    int s = ei[e], d = ei[NE + e];
    float t0 = u[s * HID + lane] + vv[d * HID + lane] + bc1_0;
    float t1 = u[s * HID + lane + 64] + vv[d * HID + lane + 64] + bc1_1;
    const float* eap = &ea[e * EDIM];
#pragma unroll 8
    for (int k = 0; k < EDIM; ++k) {
      float ev = eap[k];
      t0 = fmaf(ev, C_lds[k * HID + lane], t0);
      t1 = fmaf(ev, C_lds[k * HID + lane + 64], t1);
    }
    float sacc = fmaxf(t0, 0.f) * w2_0 + fmaxf(t1, 0.f) * w2_1;
    sacc = wsum(sacc);
    if (lane == 0) out[e] = sacc + bcc;
  }
}

extern "C" void kernel_launch(void* const* d_in, const int* in_sizes, int n_in,
                              void* d_out, int out_size, void* d_ws, size_t ws_size,
                              hipStream_t stream) {
  (void)in_sizes; (void)n_in; (void)out_size; (void)ws_size;
  const int* ei = (const int*)d_in[1];
  const float* ea = (const float*)d_in[2];
  const float* h_prev = (const float*)d_in[3];
  const float* W1 = (const float*)d_in[4];
  const float* b1 = (const float*)d_in[5];
  const float* g1 = (const float*)d_in[6];
  const float* be1 = (const float*)d_in[7];
  const float* W2 = (const float*)d_in[8];
  const float* b2 = (const float*)d_in[9];
  const float* g2 = (const float*)d_in[10];
  const float* be2 = (const float*)d_in[11];
  const float* Wih = (const float*)d_in[12];
  const float* bih = (const float*)d_in[13];
  const float* Whh = (const float*)d_in[14];
  const float* bhh = (const float*)d_in[15];
  const float* Wc1 = (const float*)d_in[16];
  const float* bc1 = (const float*)d_in[17];
  const float* Wc2 = (const float*)d_in[18];
  const float* bc2 = (const float*)d_in[19];

  char* ws = (char*)d_ws;
  float* aggr = (float*)(ws);                 // 25,600,000 B
  float* cnt  = (float*)(ws + 25600000);      //    200,000 B
  float* u    = (float*)(ws + 26214400);      // 25,600,000 B
  float* vv   = (float*)(ws + 51814400);      // 25,600,000 B (end ~77.4 MB)

  hipMemsetAsync(aggr, 0, 25800000, stream);  // aggr + cnt

  hipLaunchKernelGGL(enc_kernel, dim3(2048), dim3(256), 0, stream,
                     ea, ei, W1, b1, g1, be1, W2, b2, g2, be2, aggr, cnt);
  hipLaunchKernelGGL(gru_kernel, dim3(1563), dim3(256), 0, stream,
                     aggr, cnt, h_prev, Wih, bih, Whh, bhh, Wc1, u, vv);
  hipLaunchKernelGGL(cls_kernel, dim3(2048), dim3(256), 0, stream,
                     u, vv, ea, ei, Wc1, bc1, Wc2, bc2, (float*)d_out);
}